// Round 2
// baseline (418.824 us; speedup 1.0000x reference)
//
#include <hip/hip_runtime.h>

// Causal self-attention, S=4096, E=D=1024, fp32 in/out.
// Strategy: bf16x3 (hi/lo split) MFMA for Q/K path + QK^T (argmax-flip safe),
// plain bf16 for V and P@V. Materialize S (fp32) and P (bf16) in workspace.
// ws required: 116 MB (regions reused across phases).
//
// R1 bug fixed in R2: Pb overlays dead Qh..Kl, but softmax only wrote j<=row;
// PV GEMM reads k < round_up_128(row+1) -> stale Q/K values (std~32) times V
// gave absmax ~5.7e4 (matches sqrt(64)*1024*5sigma). Softmax now zeroes
// P[row][j] for j in (row, round_up_128(row+1)).

typedef unsigned short u16;
typedef unsigned int   u32;
typedef __bf16 bf16x8 __attribute__((ext_vector_type(8)));
typedef float  f32x4  __attribute__((ext_vector_type(4)));

#define SLEN 4096
#define EDIM 1024

__device__ __forceinline__ u16 f2bf(float x) {
    union { float f; u32 u; } c; c.f = x;
    u32 r = (c.u + 0x7FFFu + ((c.u >> 16) & 1u)) >> 16;
    return (u16)r;
}
__device__ __forceinline__ float bf2f(u16 h) {
    union { u32 u; float f; } c; c.u = ((u32)h) << 16;
    return c.f;
}

// ---------------- elementwise split: v -> hi bf16, lo bf16 ----------------
__global__ __launch_bounds__(256) void k_split(const float* __restrict__ in,
                                               u16* __restrict__ hi,
                                               u16* __restrict__ lo, int n4) {
    int i = blockIdx.x * 256 + threadIdx.x;
    if (i >= n4) return;
    const float4 v = reinterpret_cast<const float4*>(in)[i];
    u16 h0 = f2bf(v.x), h1 = f2bf(v.y), h2 = f2bf(v.z), h3 = f2bf(v.w);
    ushort4 hv = make_ushort4(h0, h1, h2, h3);
    ushort4 lv = make_ushort4(f2bf(v.x - bf2f(h0)), f2bf(v.y - bf2f(h1)),
                              f2bf(v.z - bf2f(h2)), f2bf(v.w - bf2f(h3)));
    reinterpret_cast<ushort4*>(hi)[i] = hv;
    reinterpret_cast<ushort4*>(lo)[i] = lv;
}

// ------------- transpose + split: in (R x C) f32 -> out (C x R) bf16 -------
template <bool WITH_LO>
__global__ __launch_bounds__(256) void k_tsplit(const float* __restrict__ in,
                                                u16* __restrict__ oh,
                                                u16* __restrict__ ol,
                                                int R, int C) {
    __shared__ float tile[32][33];
    int tx = threadIdx.x, ty = threadIdx.y;  // 32 x 8
    int c0 = blockIdx.x * 32, r0 = blockIdx.y * 32;
#pragma unroll
    for (int r = 0; r < 4; r++)
        tile[ty + r * 8][tx] = in[(size_t)(r0 + ty + r * 8) * C + (c0 + tx)];
    __syncthreads();
#pragma unroll
    for (int r = 0; r < 4; r++) {
        float v = tile[tx][ty + r * 8];
        size_t o = (size_t)(c0 + ty + r * 8) * R + (r0 + tx);
        u16 h = f2bf(v);
        oh[o] = h;
        if constexpr (WITH_LO) ol[o] = f2bf(v - bf2f(h));
    }
}

// ---------------- NT GEMM: C[M,N] = A[M,K] * Bt[N,K]^T ---------------------
// TERMS==3: bf16x3 (Ah*Bh + Ah*Bl + Al*Bh). TERMS==1: plain bf16.
// MODE 0: full grid (x = N/128, y = M/128)
// MODE 1: lower-triangular tile enum (blockIdx.x in [0, T*(T+1)/2))
// MODE 2: full grid, K-loop limited to (tm+1)*128 (causal P@V)
template <int TERMS, int MODE>
__global__ __launch_bounds__(256) void k_gemm_nt(
    const u16* __restrict__ Ah, const u16* __restrict__ Al,
    const u16* __restrict__ Bh, const u16* __restrict__ Bl,
    float* __restrict__ C, int M, int N, int K, float alpha) {
    constexpr int NB = (TERMS == 3) ? 2 : 1;
    // [hi/lo][kblock(4)][row(128)+1 pad][8 k-contig]  (pad kills LDS write conflicts)
    __shared__ u16 sA[NB][4][129][8];
    __shared__ u16 sB[NB][4][129][8];

    int tm, tn;
    if constexpr (MODE == 1) {
        int b = blockIdx.x;
        int ti = (int)((sqrtf(8.0f * (float)b + 1.0f) - 1.0f) * 0.5f);
        while ((ti + 1) * (ti + 2) / 2 <= b) ti++;
        while (ti * (ti + 1) / 2 > b) ti--;
        tm = ti; tn = b - ti * (ti + 1) / 2;
    } else {
        tm = blockIdx.y; tn = blockIdx.x;
    }

    int kend = K;
    if constexpr (MODE == 2) kend = (tm + 1) * 128;

    const int tid = threadIdx.x;
    const int lane = tid & 63;
    const int wv = tid >> 6;
    const int wm = (wv >> 1) * 64, wn = (wv & 1) * 64;
    const int l15 = lane & 15, lq = lane >> 4;

    f32x4 acc[4][4] = {};

    const int rowA0 = tm * 128, rowB0 = tn * 128;

    for (int k0 = 0; k0 < kend; k0 += 32) {
#pragma unroll
        for (int t = 0; t < 2; t++) {
            int ch = tid + t * 256;       // 512 chunks of 8 bf16
            int m = ch >> 2, kb = ch & 3; // kb inner: 4 lanes read 64B contiguous
            const size_t ga = (size_t)(rowA0 + m) * K + k0 + kb * 8;
            *reinterpret_cast<uint4*>(&sA[0][kb][m][0]) =
                *reinterpret_cast<const uint4*>(Ah + ga);
            if constexpr (TERMS == 3)
                *reinterpret_cast<uint4*>(&sA[1][kb][m][0]) =
                    *reinterpret_cast<const uint4*>(Al + ga);
            const size_t gb = (size_t)(rowB0 + m) * K + k0 + kb * 8;
            *reinterpret_cast<uint4*>(&sB[0][kb][m][0]) =
                *reinterpret_cast<const uint4*>(Bh + gb);
            if constexpr (TERMS == 3)
                *reinterpret_cast<uint4*>(&sB[1][kb][m][0]) =
                    *reinterpret_cast<const uint4*>(Bl + gb);
        }
        __syncthreads();

        bf16x8 ah[4], bh[4];
#pragma unroll
        for (int i = 0; i < 4; i++) {
            ah[i] = *reinterpret_cast<const bf16x8*>(&sA[0][lq][wm + i * 16 + l15][0]);
            bh[i] = *reinterpret_cast<const bf16x8*>(&sB[0][lq][wn + i * 16 + l15][0]);
        }
        if constexpr (TERMS == 3) {
            bf16x8 al[4], bl[4];
#pragma unroll
            for (int i = 0; i < 4; i++) {
                al[i] = *reinterpret_cast<const bf16x8*>(&sA[1][lq][wm + i * 16 + l15][0]);
                bl[i] = *reinterpret_cast<const bf16x8*>(&sB[1][lq][wn + i * 16 + l15][0]);
            }
#pragma unroll
            for (int mi = 0; mi < 4; mi++)
#pragma unroll
                for (int ni = 0; ni < 4; ni++) {
                    acc[mi][ni] = __builtin_amdgcn_mfma_f32_16x16x32_bf16(ah[mi], bh[ni], acc[mi][ni], 0, 0, 0);
                    acc[mi][ni] = __builtin_amdgcn_mfma_f32_16x16x32_bf16(ah[mi], bl[ni], acc[mi][ni], 0, 0, 0);
                    acc[mi][ni] = __builtin_amdgcn_mfma_f32_16x16x32_bf16(al[mi], bh[ni], acc[mi][ni], 0, 0, 0);
                }
        } else {
#pragma unroll
            for (int mi = 0; mi < 4; mi++)
#pragma unroll
                for (int ni = 0; ni < 4; ni++)
                    acc[mi][ni] = __builtin_amdgcn_mfma_f32_16x16x32_bf16(ah[mi], bh[ni], acc[mi][ni], 0, 0, 0);
        }
        __syncthreads();
    }

    // epilogue: C row = (lane>>4)*4 + r, col = lane&15 within each 16x16 tile
#pragma unroll
    for (int mi = 0; mi < 4; mi++)
#pragma unroll
        for (int ni = 0; ni < 4; ni++)
#pragma unroll
            for (int r = 0; r < 4; r++) {
                int grow = rowA0 + wm + mi * 16 + lq * 4 + r;
                int gcol = rowB0 + wn + ni * 16 + l15;
                C[(size_t)grow * N + gcol] = acc[mi][ni][r] * alpha;
            }
}

// ---------------- row softmax: S fp32 (causal row 0..i) -> P bf16 ----------
// Also zeroes P[row][j] for j in (row, round_up_128(row+1)) -- the region the
// causal PV GEMM stages -- because Pb overlays dead Qh..Kl (stale data!).
__global__ __launch_bounds__(256) void k_softmax(const float* __restrict__ S,
                                                 u16* __restrict__ P) {
    __shared__ float buf[SLEN];
    __shared__ float red[4];
    int row = blockIdx.x;
    int tid = threadIdx.x;
    int lane = tid & 63, wid = tid >> 6;
    int n = row + 1;
    const float* srow = S + (size_t)row * SLEN;

    float m = -3.0e38f;
    for (int j = tid; j < n; j += 256) {
        float v = srow[j];
        buf[j] = v;
        m = fmaxf(m, v);
    }
#pragma unroll
    for (int o = 32; o; o >>= 1) m = fmaxf(m, __shfl_xor(m, o));
    if (lane == 0) red[wid] = m;
    __syncthreads();
    m = fmaxf(fmaxf(red[0], red[1]), fmaxf(red[2], red[3]));
    __syncthreads();

    float s = 0.f;
    for (int j = tid; j < n; j += 256) {
        float e = __expf(buf[j] - m);
        buf[j] = e;
        s += e;
    }
#pragma unroll
    for (int o = 32; o; o >>= 1) s += __shfl_xor(s, o);
    if (lane == 0) red[wid] = s;
    __syncthreads();
    s = red[0] + red[1] + red[2] + red[3];
    float inv = 1.0f / s;

    u16* prow = P + (size_t)row * SLEN;
    for (int j = tid; j < n; j += 256) prow[j] = f2bf(buf[j] * inv);

    // zero the masked tail the PV GEMM will stage (kend = round_up_128(n))
    int jend = ((row >> 7) + 1) << 7;
    for (int j = n + tid; j < jend; j += 256) prow[j] = 0;
}

// ---------------------------------------------------------------------------
extern "C" void kernel_launch(void* const* d_in, const int* in_sizes, int n_in,
                              void* d_out, int out_size, void* d_ws, size_t ws_size,
                              hipStream_t stream) {
    const float* x  = (const float*)d_in[0];
    const float* Wq = (const float*)d_in[1];
    const float* Wk = (const float*)d_in[2];
    const float* Wv = (const float*)d_in[3];
    float* out = (float*)d_out;
    char* ws = (char*)d_ws;
    const size_t MB = 1024 * 1024;

    // phase-1 region [0,76MB): dead before S-GEMM writes S over it
    u16* xh  = (u16*)(ws + 0 * MB);
    u16* xl  = (u16*)(ws + 8 * MB);
    u16* Wqh = (u16*)(ws + 16 * MB);
    u16* Wkh = (u16*)(ws + 18 * MB);
    u16* Wvh = (u16*)(ws + 20 * MB);
    u16* Wql = (u16*)(ws + 22 * MB);
    u16* Wkl = (u16*)(ws + 24 * MB);
    u16* Wvl = (u16*)(ws + 26 * MB);
    float* Qf = (float*)(ws + 28 * MB);
    float* Kf = (float*)(ws + 44 * MB);
    float* Vf = (float*)(ws + 60 * MB);
    // phase-2 region [76,116MB)
    u16* Qh = (u16*)(ws + 76 * MB);
    u16* Ql = (u16*)(ws + 84 * MB);
    u16* Kh = (u16*)(ws + 92 * MB);
    u16* Kl = (u16*)(ws + 100 * MB);
    u16* Vt = (u16*)(ws + 108 * MB);
    // phase-3 reuse: S over [0,64MB) (phase-1 dead), P over [76,108MB) (Qh..Kl dead)
    float* Sb = (float*)(ws + 0 * MB);
    u16*   Pb = (u16*)(ws + 76 * MB);

    dim3 b256(256);
    dim3 tb(32, 8);

    // 1) split x, transpose+split W
    k_split<<<4096, b256, 0, stream>>>(x, xh, xl, (SLEN * EDIM) / 4);
    k_tsplit<true><<<dim3(32, 32), tb, 0, stream>>>(Wq, Wqh, Wql, EDIM, EDIM);
    k_tsplit<true><<<dim3(32, 32), tb, 0, stream>>>(Wk, Wkh, Wkl, EDIM, EDIM);
    k_tsplit<true><<<dim3(32, 32), tb, 0, stream>>>(Wv, Wvh, Wvl, EDIM, EDIM);

    // 2) Q/K/V = x @ W  (bf16x3, fp32 out)
    k_gemm_nt<3, 0><<<dim3(8, 32), b256, 0, stream>>>(xh, xl, Wqh, Wql, Qf, SLEN, EDIM, EDIM, 1.0f);
    k_gemm_nt<3, 0><<<dim3(8, 32), b256, 0, stream>>>(xh, xl, Wkh, Wkl, Kf, SLEN, EDIM, EDIM, 1.0f);
    k_gemm_nt<3, 0><<<dim3(8, 32), b256, 0, stream>>>(xh, xl, Wvh, Wvl, Vf, SLEN, EDIM, EDIM, 1.0f);

    // 3) split Q,K; transpose V
    k_split<<<4096, b256, 0, stream>>>(Qf, Qh, Ql, (SLEN * EDIM) / 4);
    k_split<<<4096, b256, 0, stream>>>(Kf, Kh, Kl, (SLEN * EDIM) / 4);
    k_tsplit<false><<<dim3(32, 128), tb, 0, stream>>>(Vf, Vt, nullptr, SLEN, EDIM);

    // 4) S = Q @ K^T / 32, lower-triangular tiles only (528 = 32*33/2)
    k_gemm_nt<3, 1><<<dim3(528), b256, 0, stream>>>(Qh, Ql, Kh, Kl, Sb, SLEN, SLEN, EDIM, 0.03125f);

    // 5) row softmax -> P bf16 (zeroes stale tail up to 128-boundary)
    k_softmax<<<SLEN, b256, 0, stream>>>(Sb, Pb);

    // 6) out = P @ V (causal K-limit per row tile)
    k_gemm_nt<1, 2><<<dim3(8, 32), b256, 0, stream>>>(Pb, nullptr, Vt, nullptr, out, SLEN, EDIM, SLEN, 1.0f);
}

// Round 3
// 330.685 us; speedup vs baseline: 1.2665x; 1.2665x over previous
//
#include <hip/hip_runtime.h>

// Causal self-attention, S=4096, E=D=1024, fp32 in/out.
// R3: (1) PV split-K (KC=1024, atomics) -- was 89.9us @ 1 block/CU, critical
//     path 128 k-iters; (2) QK fused z-dispatch, V as TERMS=1, hi/lo split
//     fused into GEMM epilogues; (3) global_load_lds width=16 staging,
//     unpadded [128][32] LDS (lane-contiguous, per m97 ladder step).
// S stored packed per lower-tri tile (528 * 64KB = 33MB). ws max 109MB.

typedef unsigned short u16;
typedef unsigned int   u32;
typedef __bf16 bf16x8 __attribute__((ext_vector_type(8)));
typedef float  f32x4  __attribute__((ext_vector_type(4)));

#define SLEN 4096
#define EDIM 1024

__device__ __forceinline__ u16 f2bf(float x) {
    union { float f; u32 u; } c; c.f = x;
    return (u16)((c.u + 0x7FFFu + ((c.u >> 16) & 1u)) >> 16);
}
__device__ __forceinline__ float bf2f(u16 h) {
    union { u32 u; float f; } c; c.u = ((u32)h) << 16;
    return c.f;
}

__device__ __forceinline__ void gll16(const u16* g, u16* l) {
    __builtin_amdgcn_global_load_lds(
        (const __attribute__((address_space(1))) void*)g,
        (__attribute__((address_space(3))) void*)l, 16, 0, 0);
}

// ---------------- elementwise split: v -> hi bf16, lo bf16 ----------------
__global__ __launch_bounds__(256) void k_split(const float* __restrict__ in,
                                               u16* __restrict__ hi,
                                               u16* __restrict__ lo, int n4) {
    int i = blockIdx.x * 256 + threadIdx.x;
    if (i >= n4) return;
    const float4 v = reinterpret_cast<const float4*>(in)[i];
    u16 h0 = f2bf(v.x), h1 = f2bf(v.y), h2 = f2bf(v.z), h3 = f2bf(v.w);
    ushort4 hv = make_ushort4(h0, h1, h2, h3);
    ushort4 lv = make_ushort4(f2bf(v.x - bf2f(h0)), f2bf(v.y - bf2f(h1)),
                              f2bf(v.z - bf2f(h2)), f2bf(v.w - bf2f(h3)));
    reinterpret_cast<ushort4*>(hi)[i] = hv;
    reinterpret_cast<ushort4*>(lo)[i] = lv;
}

// ------------- transpose + split: in (R x C) f32 -> out (C x R) bf16 -------
template <bool WITH_LO>
__global__ __launch_bounds__(256) void k_tsplit(const float* __restrict__ in,
                                                u16* __restrict__ oh,
                                                u16* __restrict__ ol,
                                                int R, int C) {
    __shared__ float tile[32][33];
    int tx = threadIdx.x, ty = threadIdx.y;  // 32 x 8
    int c0 = blockIdx.x * 32, r0 = blockIdx.y * 32;
#pragma unroll
    for (int r = 0; r < 4; r++)
        tile[ty + r * 8][tx] = in[(size_t)(r0 + ty + r * 8) * C + (c0 + tx)];
    __syncthreads();
#pragma unroll
    for (int r = 0; r < 4; r++) {
        float v = tile[tx][ty + r * 8];
        size_t o = (size_t)(c0 + ty + r * 8) * R + (r0 + tx);
        u16 h = f2bf(v);
        oh[o] = h;
        if constexpr (WITH_LO) ol[o] = f2bf(v - bf2f(h));
    }
}

// ------------- bf16 transpose: in (R x C) -> out (C x R) -------------------
__global__ __launch_bounds__(256) void k_tbf16(const u16* __restrict__ in,
                                               u16* __restrict__ outp,
                                               int R, int C) {
    __shared__ u16 tile[32][33];
    int tx = threadIdx.x, ty = threadIdx.y;
    int c0 = blockIdx.x * 32, r0 = blockIdx.y * 32;
#pragma unroll
    for (int r = 0; r < 4; r++)
        tile[ty + r * 8][tx] = in[(size_t)(r0 + ty + r * 8) * C + (c0 + tx)];
    __syncthreads();
#pragma unroll
    for (int r = 0; r < 4; r++)
        outp[(size_t)(c0 + ty + r * 8) * R + (r0 + tx)] = tile[tx][ty + r * 8];
}

// ---------------- GEMM core: 128x128 tile, BK=32, global_load_lds ----------
// A[M,K] row-major (hi[,lo]), B as Bt[N,K] row-major (hi[,lo]).
// LDS layout per tile: [128 rows][4 kb][8 elems] = 8KB, lane-contiguous in
// chunk order (required by global_load_lds wave-uniform-base + lane*16).
template <int TERMS>
__device__ __forceinline__ void gemm_core(
    u16* smem,
    const u16* __restrict__ Ah, const u16* __restrict__ Al,
    const u16* __restrict__ Bh, const u16* __restrict__ Bl,
    int K, int kbeg, int kend, int rowA0, int rowB0,
    int tid, f32x4 (&acc)[4][4]) {
    constexpr int NB = (TERMS == 3) ? 2 : 1;
    const int lane = tid & 63, wv = tid >> 6;
    const int wm = (wv >> 1) * 64, wn = (wv & 1) * 64;
    const int l15 = lane & 15, lq = lane >> 4;

    const u16* srcs[2 * NB];
    if constexpr (TERMS == 3) {
        srcs[0] = Ah + (size_t)rowA0 * K;
        srcs[1] = Al + (size_t)rowA0 * K;
        srcs[2] = Bh + (size_t)rowB0 * K;
        srcs[3] = Bl + (size_t)rowB0 * K;
    } else {
        srcs[0] = Ah + (size_t)rowA0 * K;
        srcs[1] = Bh + (size_t)rowB0 * K;
    }
    const u16* sAh = smem;
    const u16* sAl = smem + 4096;
    const u16* sBh = smem + ((TERMS == 3) ? 8192 : 4096);
    const u16* sBl = smem + 12288;

    for (int k0 = kbeg; k0 < kend; k0 += 32) {
        // stage 4*NB issues of 256 chunks (16B each); tile = i>>1 (const)
#pragma unroll
        for (int i = 0; i < 4 * NB; i++) {
            int c = ((i & 1) << 8) + (wv << 6) + lane;  // chunk within tile
            int m = c >> 2, kb = c & 3;
            const u16* g = srcs[i >> 1] + (size_t)m * K + (k0 + kb * 8);
            u16* l = smem + (size_t)((i << 8) + (wv << 6) + lane) * 8;
            gll16(g, l);
        }
        __syncthreads();

        bf16x8 ah[4], bh[4];
#pragma unroll
        for (int i = 0; i < 4; i++) {
            ah[i] = *(const bf16x8*)(sAh + (wm + i * 16 + l15) * 32 + lq * 8);
            bh[i] = *(const bf16x8*)(sBh + (wn + i * 16 + l15) * 32 + lq * 8);
        }
        if constexpr (TERMS == 3) {
            bf16x8 al[4], bl[4];
#pragma unroll
            for (int i = 0; i < 4; i++) {
                al[i] = *(const bf16x8*)(sAl + (wm + i * 16 + l15) * 32 + lq * 8);
                bl[i] = *(const bf16x8*)(sBl + (wn + i * 16 + l15) * 32 + lq * 8);
            }
#pragma unroll
            for (int mi = 0; mi < 4; mi++)
#pragma unroll
                for (int ni = 0; ni < 4; ni++) {
                    acc[mi][ni] = __builtin_amdgcn_mfma_f32_16x16x32_bf16(ah[mi], bh[ni], acc[mi][ni], 0, 0, 0);
                    acc[mi][ni] = __builtin_amdgcn_mfma_f32_16x16x32_bf16(ah[mi], bl[ni], acc[mi][ni], 0, 0, 0);
                    acc[mi][ni] = __builtin_amdgcn_mfma_f32_16x16x32_bf16(al[mi], bh[ni], acc[mi][ni], 0, 0, 0);
                }
        } else {
#pragma unroll
            for (int mi = 0; mi < 4; mi++)
#pragma unroll
                for (int ni = 0; ni < 4; ni++)
                    acc[mi][ni] = __builtin_amdgcn_mfma_f32_16x16x32_bf16(ah[mi], bh[ni], acc[mi][ni], 0, 0, 0);
        }
        __syncthreads();
    }
}

// ---------------- QK fused GEMM: z in {0:Q, 1:K}, split epilogue -----------
__global__ __launch_bounds__(256) void k_gemm_qk(
    const u16* __restrict__ xh, const u16* __restrict__ xl,
    const u16* __restrict__ Bqh, const u16* __restrict__ Bql,
    const u16* __restrict__ Bkh, const u16* __restrict__ Bkl,
    u16* __restrict__ Qh, u16* __restrict__ Ql,
    u16* __restrict__ Kh, u16* __restrict__ Kl) {
    __shared__ u16 smem[16384];
    const int z = blockIdx.z;
    const u16* Bh = z ? Bkh : Bqh;
    const u16* Bl = z ? Bkl : Bql;
    u16* Oh = z ? Kh : Qh;
    u16* Ol = z ? Kl : Ql;
    f32x4 acc[4][4] = {};
    const int rowA0 = blockIdx.y * 128, rowB0 = blockIdx.x * 128;
    gemm_core<3>(smem, xh, xl, Bh, Bl, EDIM, 0, EDIM, rowA0, rowB0, threadIdx.x, acc);
    const int lane = threadIdx.x & 63, wv = threadIdx.x >> 6;
    const int wm = (wv >> 1) * 64, wn = (wv & 1) * 64;
    const int l15 = lane & 15, lq = lane >> 4;
#pragma unroll
    for (int mi = 0; mi < 4; mi++)
#pragma unroll
        for (int ni = 0; ni < 4; ni++)
#pragma unroll
            for (int r = 0; r < 4; r++) {
                size_t o = (size_t)(rowA0 + wm + mi * 16 + lq * 4 + r) * EDIM +
                           (rowB0 + wn + ni * 16 + l15);
                float v = acc[mi][ni][r];
                u16 h = f2bf(v);
                Oh[o] = h;
                Ol[o] = f2bf(v - bf2f(h));
            }
}

// ---------------- V GEMM: TERMS=1, bf16 epilogue ---------------------------
__global__ __launch_bounds__(256) void k_gemm_v(
    const u16* __restrict__ xh, const u16* __restrict__ Bvh,
    u16* __restrict__ Vbf) {
    __shared__ u16 smem[8192];
    f32x4 acc[4][4] = {};
    const int rowA0 = blockIdx.y * 128, rowB0 = blockIdx.x * 128;
    gemm_core<1>(smem, xh, nullptr, Bvh, nullptr, EDIM, 0, EDIM, rowA0, rowB0, threadIdx.x, acc);
    const int lane = threadIdx.x & 63, wv = threadIdx.x >> 6;
    const int wm = (wv >> 1) * 64, wn = (wv & 1) * 64;
    const int l15 = lane & 15, lq = lane >> 4;
#pragma unroll
    for (int mi = 0; mi < 4; mi++)
#pragma unroll
        for (int ni = 0; ni < 4; ni++)
#pragma unroll
            for (int r = 0; r < 4; r++) {
                size_t o = (size_t)(rowA0 + wm + mi * 16 + lq * 4 + r) * EDIM +
                           (rowB0 + wn + ni * 16 + l15);
                Vbf[o] = f2bf(acc[mi][ni][r]);
            }
}

// ---------------- S GEMM: lower-tri tiles, packed output -------------------
__global__ __launch_bounds__(256) void k_gemm_s(
    const u16* __restrict__ Qh, const u16* __restrict__ Ql,
    const u16* __restrict__ Kh, const u16* __restrict__ Kl,
    float* __restrict__ Spk) {
    __shared__ u16 smem[16384];
    int b = blockIdx.x;
    int ti = (int)((sqrtf(8.0f * (float)b + 1.0f) - 1.0f) * 0.5f);
    while ((ti + 1) * (ti + 2) / 2 <= b) ti++;
    while (ti * (ti + 1) / 2 > b) ti--;
    int tm = ti, tn = b - ti * (ti + 1) / 2;
    f32x4 acc[4][4] = {};
    gemm_core<3>(smem, Qh, Ql, Kh, Kl, EDIM, 0, EDIM, tm * 128, tn * 128, threadIdx.x, acc);
    const int lane = threadIdx.x & 63, wv = threadIdx.x >> 6;
    const int wm = (wv >> 1) * 64, wn = (wv & 1) * 64;
    const int l15 = lane & 15, lq = lane >> 4;
    float* Cb = Spk + (size_t)b * 16384;
#pragma unroll
    for (int mi = 0; mi < 4; mi++)
#pragma unroll
        for (int ni = 0; ni < 4; ni++)
#pragma unroll
            for (int r = 0; r < 4; r++)
                Cb[(wm + mi * 16 + lq * 4 + r) * 128 + (wn + ni * 16 + l15)] =
                    acc[mi][ni][r] * 0.03125f;
}

// ---------------- PV GEMM: split-K (KC=1024), atomic for tm>=8 -------------
__global__ __launch_bounds__(256) void k_gemm_pv(
    const u16* __restrict__ P, const u16* __restrict__ Vt,
    float* __restrict__ C) {
    __shared__ u16 smem[8192];
    int tn = blockIdx.x;
    int y = blockIdx.y, tm = 0;
    for (;;) {
        int nc = (tm + 8) >> 3;  // ceil((tm+1)/8)
        if (y < nc) break;
        y -= nc; tm++;
    }
    int kbeg = y * 1024;
    int kend = min((tm + 1) * 128, kbeg + 1024);
    f32x4 acc[4][4] = {};
    gemm_core<1>(smem, P, nullptr, Vt, nullptr, SLEN, kbeg, kend, tm * 128, tn * 128, threadIdx.x, acc);
    const int lane = threadIdx.x & 63, wv = threadIdx.x >> 6;
    const int wm = (wv >> 1) * 64, wn = (wv & 1) * 64;
    const int l15 = lane & 15, lq = lane >> 4;
    bool multi = (tm >= 8);
#pragma unroll
    for (int mi = 0; mi < 4; mi++)
#pragma unroll
        for (int ni = 0; ni < 4; ni++)
#pragma unroll
            for (int r = 0; r < 4; r++) {
                size_t o = (size_t)(tm * 128 + wm + mi * 16 + lq * 4 + r) * EDIM +
                           (tn * 128 + wn + ni * 16 + l15);
                if (multi) atomicAdd(&C[o], acc[mi][ni][r]);
                else       C[o] = acc[mi][ni][r];
            }
}

// ---------------- row softmax over packed S -> P bf16 ----------------------
__global__ __launch_bounds__(256) void k_softmax(const float* __restrict__ Spk,
                                                 u16* __restrict__ P) {
    __shared__ float buf[SLEN];
    __shared__ float red[4];
    int row = blockIdx.x;
    int tid = threadIdx.x;
    int lane = tid & 63, wid = tid >> 6;
    int n = row + 1;
    int tm = row >> 7, rl = row & 127;
    const float* srow = Spk + (size_t)(tm * (tm + 1) / 2) * 16384 + rl * 128;

    float m = -3.0e38f;
    for (int j = tid; j < n; j += 256) {
        float v = srow[(size_t)(j >> 7) * 16384 + (j & 127)];
        buf[j] = v;
        m = fmaxf(m, v);
    }
#pragma unroll
    for (int o = 32; o; o >>= 1) m = fmaxf(m, __shfl_xor(m, o));
    if (lane == 0) red[wid] = m;
    __syncthreads();
    m = fmaxf(fmaxf(red[0], red[1]), fmaxf(red[2], red[3]));
    __syncthreads();

    float s = 0.f;
    for (int j = tid; j < n; j += 256) {
        float e = __expf(buf[j] - m);
        buf[j] = e;
        s += e;
    }
#pragma unroll
    for (int o = 32; o; o >>= 1) s += __shfl_xor(s, o);
    if (lane == 0) red[wid] = s;
    __syncthreads();
    s = red[0] + red[1] + red[2] + red[3];
    float inv = 1.0f / s;

    u16* prow = P + (size_t)row * SLEN;
    for (int j = tid; j < n; j += 256) prow[j] = f2bf(buf[j] * inv);
    // zero tail up to 128-boundary (PV stages it; P overlays dead Qh..Kl)
    int jend = ((row >> 7) + 1) << 7;
    for (int j = n + tid; j < jend; j += 256) prow[j] = 0;
}

// ---------------------------------------------------------------------------
extern "C" void kernel_launch(void* const* d_in, const int* in_sizes, int n_in,
                              void* d_out, int out_size, void* d_ws, size_t ws_size,
                              hipStream_t stream) {
    const float* x  = (const float*)d_in[0];
    const float* Wq = (const float*)d_in[1];
    const float* Wk = (const float*)d_in[2];
    const float* Wv = (const float*)d_in[3];
    float* out = (float*)d_out;
    char* ws = (char*)d_ws;
    const size_t MB = 1024 * 1024;

    u16* xh  = (u16*)(ws + 0 * MB);    // 8MB
    u16* xl  = (u16*)(ws + 8 * MB);    // 8MB
    u16* Wqh = (u16*)(ws + 16 * MB);   // 2MB each
    u16* Wkh = (u16*)(ws + 18 * MB);
    u16* Wvh = (u16*)(ws + 20 * MB);
    u16* Wql = (u16*)(ws + 22 * MB);
    u16* Wkl = (u16*)(ws + 24 * MB);
    u16* Qh  = (u16*)(ws + 28 * MB);   // 8MB each
    u16* Ql  = (u16*)(ws + 36 * MB);
    u16* Kh  = (u16*)(ws + 44 * MB);
    u16* Kl  = (u16*)(ws + 52 * MB);
    u16* Vbf = (u16*)(ws + 60 * MB);   // 8MB
    u16* Vt  = (u16*)(ws + 68 * MB);   // 8MB
    float* Spk = (float*)(ws + 76 * MB);  // 33MB packed tri tiles -> [76,109)
    u16* Pb  = (u16*)(ws + 28 * MB);   // 32MB, overlays dead Qh..Kl

    dim3 b256(256);
    dim3 tb(32, 8);

    // 1) split x; transpose+split Wq,Wk; transpose Wv (hi only)
    k_split<<<4096, b256, 0, stream>>>(x, xh, xl, (SLEN * EDIM) / 4);
    k_tsplit<true ><<<dim3(32, 32), tb, 0, stream>>>(Wq, Wqh, Wql, EDIM, EDIM);
    k_tsplit<true ><<<dim3(32, 32), tb, 0, stream>>>(Wk, Wkh, Wkl, EDIM, EDIM);
    k_tsplit<false><<<dim3(32, 32), tb, 0, stream>>>(Wv, Wvh, nullptr, EDIM, EDIM);

    // 2) Q,K = x@W (bf16x3, split epilogue); V = x@Wv (bf16); transpose V
    k_gemm_qk<<<dim3(8, 32, 2), b256, 0, stream>>>(xh, xl, Wqh, Wql, Wkh, Wkl,
                                                   Qh, Ql, Kh, Kl);
    k_gemm_v<<<dim3(8, 32), b256, 0, stream>>>(xh, Wvh, Vbf);
    k_tbf16<<<dim3(32, 128), tb, 0, stream>>>(Vbf, Vt, SLEN, EDIM);

    // 3) S = QK^T/32, packed lower-tri tiles (528 blocks)
    k_gemm_s<<<dim3(528), b256, 0, stream>>>(Qh, Ql, Kh, Kl, Spk);

    // 4) softmax -> P bf16 (zeroes tail to 128-boundary)
    k_softmax<<<SLEN, b256, 0, stream>>>(Spk, Pb);

    // 5) out = P@V, split-K KC=1024 (grid 8 x 80), atomics for tm>=8
    hipMemsetAsync(d_out, 0, (size_t)out_size * sizeof(float), stream);
    k_gemm_pv<<<dim3(8, 80), b256, 0, stream>>>(Pb, Vt, out);
}